// Round 8
// baseline (730.329 us; speedup 1.0000x reference)
//
#include <hip/hip_runtime.h>
#include <math.h>

// Problem dims (AttentionRNN): B=128, T=64, H=256, V=128
#define BB 128
#define TT 64
#define HH 256
#define G3 768   // 3*H
#define VV 128

typedef _Float16 half8 __attribute__((ext_vector_type(8)));
typedef _Float16 half4v __attribute__((ext_vector_type(4)));
typedef float f32x4 __attribute__((ext_vector_type(4)));

// ---------------------------------------------------------------------------
// f32 -> f16 cast, 4 elems/thread (n4 = n/4)
// ---------------------------------------------------------------------------
__global__ __launch_bounds__(256) void cast_f16(const float* __restrict__ in,
                                                _Float16* __restrict__ out, int n4) {
    int i = blockIdx.x * 256 + threadIdx.x;
    if (i < n4) {
        float4 v = ((const float4*)in)[i];
        half4v h = {(_Float16)v.x, (_Float16)v.y, (_Float16)v.z, (_Float16)v.w};
        ((half4v*)out)[i] = h;
    }
}

// ---------------------------------------------------------------------------
// Pack w_hh [768][256] f32 -> f16 MFMA B-fragments, in the exact per-lane
// order gru_mfma consumes: [wave 8][tile 6][ktile 8][lane 64][elem 8].
// Fragment def (v_mfma_f32_16x16x32_f16 B): col = lane&15, k = (lane>>4)*8+e.
// Tile tau: gate g = tau/2, sub s = tau&1 -> ncol = g*256 + wave*32 + s*16.
// ---------------------------------------------------------------------------
__global__ __launch_bounds__(256) void pack_whh_f16(const float* __restrict__ w,
                                                    _Float16* __restrict__ out) {
    int d = blockIdx.x * 256 + threadIdx.x;   // 196608 total
    int e   = d & 7;
    int l   = (d >> 3) & 63;
    int kap = (d >> 9) & 7;
    int wt  = d >> 12;                        // wave*6 + tau
    int wv  = wt / 6, tau = wt % 6;
    int ncol = (tau >> 1) * 256 + wv * 32 + (tau & 1) * 16 + (l & 15);
    int k    = kap * 32 + (l >> 4) * 8 + e;
    out[d] = (_Float16)w[ncol * HH + k];
}

// Folded bias: out[j] = b_ih[j] + (j<512 ? b_hh[j] : 0).  (r,z parts of b_hh
// ride along in xp; the n part stays separate since it's scaled by r.)
__global__ __launch_bounds__(256) void prep_bias(const float* __restrict__ b_ih,
                                                 const float* __restrict__ b_hh,
                                                 float* __restrict__ outb) {
    int j = blockIdx.x * 256 + threadIdx.x;   // 768
    outb[j] = b_ih[j] + (j < 2 * HH ? b_hh[j] : 0.f);
}

// ---------------------------------------------------------------------------
// f16 MFMA GEMM: C[M,N] = A[M,K1+K2] @ B[N,K1+K2]^T + bias (f32 accum).
// A given as two f16 slabs (split-K concat) so logits reads [enc|ctx].
// 64x64 tile, 256 threads = 4 waves; wave w owns cols [w*16,(w+1)*16).
// K-step 32 via mfma_f32_16x16x32_f16 (fragment mapping proven in gru_mfma).
// omode 0: f32 C.  1: f16 C.  2: f16 C + t-major row permute
//         (r = b*64+t -> orow = t*128+b).
// ---------------------------------------------------------------------------
__global__ __launch_bounds__(256) void gemm_f16(
    const _Float16* __restrict__ A1, int lda1, int K1,
    const _Float16* __restrict__ A2, int lda2, int K2,
    const _Float16* __restrict__ Bw, int ldb,
    const float* __restrict__ bias,
    void* __restrict__ Cv, int ldc, int M, int N, int omode)
{
    __shared__ alignas(16) _Float16 As[64][36];   // +4 pad: 72B row stride
    __shared__ alignas(16) _Float16 Bs[64][36];
    const int tid = threadIdx.x;
    const int wv = tid >> 6, l = tid & 63;
    const int l15 = l & 15, lhi = l >> 4;
    const int row0 = blockIdx.y * 64, col0 = blockIdx.x * 64;
    const int ar = tid >> 2, ac = (tid & 3) * 8;   // stage: 1x16B per thread
    const int KT = K1 + K2;

    f32x4 acc[4];
#pragma unroll
    for (int m = 0; m < 4; ++m) acc[m] = (f32x4)0.f;

    for (int k0 = 0; k0 < KT; k0 += 32) {
        const _Float16* Ap; int lda, kk0;
        if (k0 < K1) { Ap = A1; lda = lda1; kk0 = k0; }
        else         { Ap = A2; lda = lda2; kk0 = k0 - K1; }
        *(half8*)&As[ar][ac] = *(const half8*)&Ap[(long)(row0 + ar) * lda + kk0 + ac];
        *(half8*)&Bs[ar][ac] = *(const half8*)&Bw[(long)(col0 + ar) * ldb + k0 + ac];
        __syncthreads();
        const half8 bfrag = *(const half8*)&Bs[wv * 16 + l15][lhi * 8];
#pragma unroll
        for (int m = 0; m < 4; ++m) {
            const half8 afrag = *(const half8*)&As[m * 16 + l15][lhi * 8];
            acc[m] = __builtin_amdgcn_mfma_f32_16x16x32_f16(afrag, bfrag, acc[m], 0, 0, 0);
        }
        __syncthreads();
    }

    const int col = col0 + wv * 16 + l15;
    const float bb = bias ? bias[col] : 0.f;
#pragma unroll
    for (int m = 0; m < 4; ++m) {
#pragma unroll
        for (int reg = 0; reg < 4; ++reg) {
            const int r = row0 + m * 16 + lhi * 4 + reg;
            const float v = acc[m][reg] + bb;
            if (omode == 0) {
                ((float*)Cv)[(long)r * ldc + col] = v;
            } else {
                const int orow = (omode == 2) ? ((r & 63) * BB + (r >> 6)) : r;
                ((_Float16*)Cv)[(long)orow * ldc + col] = (_Float16)v;
            }
        }
    }
}

// ---------------------------------------------------------------------------
// MFMA GRU layer, register-resident weights (the 192us round-3 structure;
// only change: xp and out_seq are f16).
// 8 blocks x 16 batch rows, 512 threads (8 waves), 1 block/CU.
// Per step: 8 ds_read A-frags -> 48 MFMA -> barrier -> gates (xp scalar
// loads in-phase) -> write hbuf + out_seq(f16) -> barrier.
// xsrc: f16 rows of 768. mode 0: row = token id. mode 1: row = t*128+batch.
// ---------------------------------------------------------------------------
__global__ __launch_bounds__(512, 2) void gru_mfma(
    const _Float16* __restrict__ wp,  // packed fragments (see pack_whh_f16)
    const float* __restrict__ b_hh,   // [768]; only [512:768) used here
    const _Float16* __restrict__ xsrc,// f16 xp rows of 768
    const int*   __restrict__ xidx,   // token ids (mode0)
    _Float16* __restrict__ out_seq,   // [B*T][256] f16
    float* __restrict__ hlast,        // [B][256] f32 (mode1 only)
    int mode)
{
    __shared__ alignas(16) _Float16 hbuf[16][264];   // +8 pad
    __shared__ int tok[16][TT];                      // mode0 token ids
    const int tid = threadIdx.x;
    const int wv = tid >> 6, l = tid & 63;
    const int l15 = l & 15, lhi = l >> 4;
    const int r0 = blockIdx.x * 16;

    for (int i = tid; i < 16 * 264; i += 512) ((_Float16*)hbuf)[i] = (_Float16)0.f;
    if (mode == 0) {
        ((int*)tok)[tid]       = xidx[r0 * TT + tid];
        ((int*)tok)[tid + 512] = xidx[r0 * TT + tid + 512];
    }

    // ---- load all 48 weight fragments into registers (once) ----
    half8 W[48];
    const half8* wp8 = (const half8*)wp;
    const int fb = wv * 48 * 64;
#pragma unroll
    for (int f = 0; f < 48; ++f) W[f] = wp8[fb + f * 64 + l];

    const int colbase = wv * 32 + l15;
    const float bhn0 = b_hh[2 * HH + colbase];
    const float bhn1 = b_hh[2 * HH + colbase + 16];
    float hold[2][4] = {};
    __syncthreads();

    for (int t = 0; t < TT; ++t) {
        f32x4 acc[6];
#pragma unroll
        for (int tau = 0; tau < 6; ++tau) acc[tau] = (f32x4)0.f;

#pragma unroll
        for (int kap = 0; kap < 8; ++kap) {
            const half8 a = *(const half8*)&hbuf[l15][kap * 32 + lhi * 8];
#pragma unroll
            for (int tau = 0; tau < 6; ++tau)
                acc[tau] = __builtin_amdgcn_mfma_f32_16x16x32_f16(
                    a, W[tau * 8 + kap], acc[tau], 0, 0, 0);
        }
        __syncthreads();   // all waves' A-reads done before h is overwritten

        // gates: C-layout col = l&15, row = (l>>4)*4 + reg
#pragma unroll
        for (int s = 0; s < 2; ++s) {
            const int col = colbase + s * 16;
            const float bhn = s ? bhn1 : bhn0;
#pragma unroll
            for (int reg = 0; reg < 4; ++reg) {
                const int row = lhi * 4 + reg;
                const long base = (mode == 0)
                    ? (long)tok[row][t] * G3
                    : ((long)t * BB + (r0 + row)) * G3;
                const float xr  = (float)xsrc[base + col];
                const float xz  = (float)xsrc[base + col + HH];
                const float xnv = (float)xsrc[base + col + 2 * HH];
                const float pr = acc[0 + s][reg] + xr;
                const float pz = acc[2 + s][reg] + xz;
                const float hn = acc[4 + s][reg] + bhn;
                const float rg = 1.f / (1.f + __expf(-pr));
                const float zg = 1.f / (1.f + __expf(-pz));
                const float npre = xnv + rg * hn;
                const float e2 = __expf(2.f * npre);
                const float ng = (e2 - 1.f) / (e2 + 1.f);
                const float hnew = (1.f - zg) * ng + zg * hold[s][reg];
                hold[s][reg] = hnew;
                hbuf[row][col] = (_Float16)hnew;
                out_seq[((long)(r0 + row) * TT + t) * HH + col] = (_Float16)hnew;
                if (mode == 1 && t == TT - 1) hlast[(r0 + row) * HH + col] = hnew;
            }
        }
        __syncthreads();
    }
}

// ---------------------------------------------------------------------------
// Bahdanau attention, one block per (b,t): energy -> softmax(k) -> ctx.
// WU (f32) holds [Wa_e | Ua_h] per row (stride 512); enc f16; ctx out f16.
// ---------------------------------------------------------------------------
__device__ __forceinline__ float tanh_fast(float x) {
    const float e = __expf(2.f * x);
    return (e - 1.f) / (e + 1.f);
}

__global__ __launch_bounds__(256) void attn_kernel(
    const float* __restrict__ WU,      // [B*T][512]
    const _Float16* __restrict__ enc,  // [B*T][256] f16
    const float* __restrict__ v_a,     // [256]
    _Float16* __restrict__ ctx)        // [B*T][256] f16
{
    __shared__ float q[HH], va[HH], sm[TT];
    const int tid = threadIdx.x;
    const int t = blockIdx.x, b = blockIdx.y;

    q[tid]  = WU[(b * TT + t) * 512 + 256 + tid];
    va[tid] = v_a[tid];
    __syncthreads();

    const int w = tid >> 6, lane = tid & 63;
#pragma unroll 4
    for (int i = 0; i < 16; ++i) {
        const int k = w * 16 + i;
        const float* we = WU + (b * TT + k) * 512;
        float s = 0.f;
#pragma unroll
        for (int c = 0; c < 4; ++c) {
            const int h = lane + 64 * c;
            s += va[h] * tanh_fast(we[h] + q[h]);
        }
#pragma unroll
        for (int off = 32; off > 0; off >>= 1) s += __shfl_xor(s, off);
        if (lane == 0) sm[k] = s;
    }
    __syncthreads();

    if (tid < TT) {
        const float e = sm[tid];
        float mx = e;
#pragma unroll
        for (int off = 32; off > 0; off >>= 1) mx = fmaxf(mx, __shfl_xor(mx, off));
        const float p = __expf(e - mx);
        float sum = p;
#pragma unroll
        for (int off = 32; off > 0; off >>= 1) sum += __shfl_xor(sum, off);
        sm[tid] = p / sum;
    }
    __syncthreads();

    float c = 0.f;
    for (int k = 0; k < TT; ++k)
        c += sm[k] * (float)enc[(b * TT + k) * HH + tid];
    ctx[(b * TT + t) * HH + tid] = (_Float16)c;
}

// ---------------------------------------------------------------------------
extern "C" void kernel_launch(void* const* d_in, const int* in_sizes, int n_in,
                              void* d_out, int out_size, void* d_ws, size_t ws_size,
                              hipStream_t stream) {
    const int*   x     = (const int*)  d_in[0];
    const float* embed = (const float*)d_in[1];
    const float* w_ih0 = (const float*)d_in[2];
    const float* w_hh0 = (const float*)d_in[3];
    const float* b_ih0 = (const float*)d_in[4];
    const float* b_hh0 = (const float*)d_in[5];
    const float* w_ih1 = (const float*)d_in[6];
    const float* w_hh1 = (const float*)d_in[7];
    const float* b_ih1 = (const float*)d_in[8];
    const float* b_hh1 = (const float*)d_in[9];
    const float* W_a   = (const float*)d_in[10];
    const float* U_a   = (const float*)d_in[11];
    const float* v_a   = (const float*)d_in[12];
    const float* fc_W  = (const float*)d_in[13];
    const float* fc_b  = (const float*)d_in[14];
    float* out = (float*)d_out;

    // workspace layout (float words)
    float* ws = (float*)d_ws;
    _Float16* wT0    = (_Float16*)ws;             // 196608 f16 = 98304 f
    _Float16* wT1    = (_Float16*)(ws + 98304);   // 98304 f
    float*    bias0  = ws + 196608;               // 768
    float*    bias1  = ws + 197376;               // 768
    _Float16* embh   = (_Float16*)(ws + 198144);  // 32768 f16 = 16384 f
    _Float16* wih0h  = (_Float16*)(ws + 214528);  // 196608 f16 = 98304 f
    _Float16* wih1h  = (_Float16*)(ws + 312832);  // 98304 f
    _Float16* WUBh   = (_Float16*)(ws + 411136);  // 131072 f16 = 65536 f
    _Float16* fcWh   = (_Float16*)(ws + 476672);  // 65536 f16 = 32768 f
    _Float16* P0h    = (_Float16*)(ws + 509440);  // 98304 f16 = 49152 f
    _Float16* h1h    = (_Float16*)(ws + 558592);  // 2097152 f16 = 1048576 f
    _Float16* ench   = (_Float16*)(ws + 1607168); // 1048576 f
    _Float16* ctxh   = (_Float16*)(ws + 2655744); // 1048576 f
    _Float16* xp1h   = (_Float16*)(ws + 3704320); // 6291456 f16 = 3145728 f
    float*    WU     = ws + 3704320;              // alias (xp1 dead): 4194304 f

    float* logits = out;                  // [8192][128]
    float* hlast  = out + BB * TT * VV;   // [128][256]

    // 1) casts + weight packing + bias folding
    cast_f16<<<32, 256, 0, stream>>>(embed, embh, VV * HH / 4);
    cast_f16<<<192, 256, 0, stream>>>(w_ih0, wih0h, G3 * HH / 4);
    cast_f16<<<192, 256, 0, stream>>>(w_ih1, wih1h, G3 * HH / 4);
    cast_f16<<<64, 256, 0, stream>>>(W_a, WUBh, HH * HH / 4);
    cast_f16<<<64, 256, 0, stream>>>(U_a, WUBh + HH * HH, HH * HH / 4);
    cast_f16<<<64, 256, 0, stream>>>(fc_W, fcWh, VV * 2 * HH / 4);
    pack_whh_f16<<<768, 256, 0, stream>>>(w_hh0, wT0);
    pack_whh_f16<<<768, 256, 0, stream>>>(w_hh1, wT1);
    prep_bias<<<3, 256, 0, stream>>>(b_ih0, b_hh0, bias0);
    prep_bias<<<3, 256, 0, stream>>>(b_ih1, b_hh1, bias1);

    // 2) P0 = embed @ w_ih0.T + bias0  -> f16 [128][768]
    gemm_f16<<<dim3(G3 / 64, VV / 64), 256, 0, stream>>>(
        embh, HH, HH, nullptr, 0, 0, wih0h, HH, bias0, P0h, G3, VV, G3, 1);

    // 3) GRU layer 0 (xp gathered from P0 by token id) -> h1 f16
    gru_mfma<<<BB / 16, 512, 0, stream>>>(wT0, b_hh0, P0h, x, h1h, nullptr, 0);

    // 4) xp1 = h1 @ w_ih1.T + bias1 -> f16, t-major rows [64][128][768]
    gemm_f16<<<dim3(G3 / 64, BB * TT / 64), 256, 0, stream>>>(
        h1h, HH, HH, nullptr, 0, 0, wih1h, HH, bias1, xp1h, G3, BB * TT, G3, 2);

    // 5) GRU layer 1 -> enc f16, h_last f32
    gru_mfma<<<BB / 16, 512, 0, stream>>>(wT1, b_hh1, xp1h, nullptr, ench, hlast, 1);

    // 6) WU = enc @ [W_a;U_a].T -> f32 [8192][512]  (merged Wae/Uah)
    gemm_f16<<<dim3(512 / 64, BB * TT / 64), 256, 0, stream>>>(
        ench, HH, HH, nullptr, 0, 0, WUBh, HH, nullptr, WU, 512, BB * TT, 512, 0);

    // 7) attention: energy -> softmax -> ctx (f16)
    attn_kernel<<<dim3(TT, BB), 256, 0, stream>>>(WU, ench, v_a, ctxh);

    // 8) logits = [enc | ctx] @ fc_W.T + fc_b -> f32  (split-A, K=256+256)
    gemm_f16<<<dim3(VV / 64, BB * TT / 64), 256, 0, stream>>>(
        ench, HH, HH, ctxh, HH, HH, fcWh, 2 * HH, fc_b, logits, VV, BB * TT, VV, 0);
}